// Round 1
// baseline (387.512 us; speedup 1.0000x reference)
//
#include <hip/hip_runtime.h>
#include <cstddef>

// Problem constants (match reference): B=32, D=64, T=8192, K=512
#define B_ 32
#define D_ 64
#define T_ 8192
#define K_ 512

typedef float v2f __attribute__((ext_vector_type(2)));

// ---------------------------------------------------------------------------
// One thread per (b,t). Bit-replicates the numpy fp32 pipeline (verified
// absmax==0):
//   x2  = np.sum(xp*xp, -1)        -> pairwise 8-accumulator block (n=64)
//   e2  = np.sum(emb*emb, -1)      -> same pairwise scheme (precomputed in LDS)
//   xe  = np.einsum('btd,kd->btk') -> npyv AVX512 dot: 16 lanes, 4-deep fused
//                                     FMA chain + 8/4/2/1 pairwise reduce
//   dist = fma(-2, xe, x2) + e2    -> identical to (x2 - 2*xe) + e2 since
//                                     2*xe is exact and fma rounds once
//   argmin: strict <, first index wins (np.argmin tie-break)
//
// ROUND-3 CHANGE (allocation only, zero arithmetic change):
//   rocprof showed VGPR_Count=48 despite __launch_bounds__(256,4): the LLVM
//   scheduler treats waves-per-eu as a FLOOR and still targeted ~10-wave
//   occupancy, evicting the 64-float x column from VGPRs and paying ~60
//   extra instrs per k inside the 512-deep loop (VALU-busy 182us vs 75us
//   ideal).  Grid supplies only 4 waves/SIMD, so high occupancy is useless.
//   Fix: amdgpu_waves_per_eu(4,4) pins min==max==4 -> RA gets the full
//   128-VGPR budget and stops economizing.  Plus empty-asm value barriers
//   on xr so the loads cannot be rematerialized/sunk into the K loop.
// ---------------------------------------------------------------------------
__global__ __launch_bounds__(256)
__attribute__((amdgpu_waves_per_eu(4, 4)))
void vq_kernel(const float* __restrict__ x,
               const float* __restrict__ emb,
               float* __restrict__ out) {
    __shared__ float s_e2[K_];

    // ---- e2 precompute into LDS, numpy pairwise-8 order, no FMA contraction
    {
#pragma clang fp contract(off)
        for (int k = threadIdx.x; k < K_; k += 256) {
            const float* er = emb + k * D_;
            float r[8];
#pragma unroll
            for (int j = 0; j < 8; ++j) r[j] = er[j] * er[j];
#pragma unroll
            for (int i = 8; i < 64; i += 8) {
#pragma unroll
                for (int j = 0; j < 8; ++j) {
                    float p = er[i + j] * er[i + j];
                    r[j] = r[j] + p;
                }
            }
            s_e2[k] = ((r[0] + r[1]) + (r[2] + r[3])) + ((r[4] + r[5]) + (r[6] + r[7]));
        }
    }
    __syncthreads();

    const int t = blockIdx.x * 256 + threadIdx.x;
    const int b = blockIdx.y;
    const float* xp = x + ((size_t)b * D_) * T_ + t;

    // ---- load x[b, :, t] into 32 packed v2f regs (coalesced across lanes)
    v2f xr[D_ / 2];
#pragma unroll
    for (int j = 0; j < D_ / 2; ++j) {
        v2f p;
        p[0] = xp[(size_t)(2 * j) * T_];
        p[1] = xp[(size_t)(2 * j + 1) * T_];
        xr[j] = p;
    }
    // Value barriers: make xr defs opaque so the compiler can neither
    // rematerialize the global loads inside the K loop nor sink them.
    // (8 operands per asm to stay under the operand limit.)
    asm volatile("" : "+v"(xr[0]), "+v"(xr[1]), "+v"(xr[2]), "+v"(xr[3]),
                      "+v"(xr[4]), "+v"(xr[5]), "+v"(xr[6]), "+v"(xr[7]));
    asm volatile("" : "+v"(xr[8]), "+v"(xr[9]), "+v"(xr[10]), "+v"(xr[11]),
                      "+v"(xr[12]), "+v"(xr[13]), "+v"(xr[14]), "+v"(xr[15]));
    asm volatile("" : "+v"(xr[16]), "+v"(xr[17]), "+v"(xr[18]), "+v"(xr[19]),
                      "+v"(xr[20]), "+v"(xr[21]), "+v"(xr[22]), "+v"(xr[23]));
    asm volatile("" : "+v"(xr[24]), "+v"(xr[25]), "+v"(xr[26]), "+v"(xr[27]),
                      "+v"(xr[28]), "+v"(xr[29]), "+v"(xr[30]), "+v"(xr[31]));
#define XD(d) (xr[(d) >> 1][(d) & 1])

    // ---- x2 via numpy pairwise-8 (products first, then sequential adds)
    float x2;
    {
#pragma clang fp contract(off)
        float r[8];
#pragma unroll
        for (int j = 0; j < 8; ++j) r[j] = XD(j) * XD(j);
#pragma unroll
        for (int i = 8; i < 64; i += 8) {
#pragma unroll
            for (int j = 0; j < 8; ++j) {
                float p = XD(i + j) * XD(i + j);
                r[j] = r[j] + p;
            }
        }
        x2 = ((r[0] + r[1]) + (r[2] + r[3])) + ((r[4] + r[5]) + (r[6] + r[7]));
    }

    // ---- K-loop: replicate einsum npyv dot (AVX512: vstep=16, one x4 iter)
    float best = 3.4e38f;
    int bi = 0;
    {
#pragma clang fp contract(off)
        for (int k = 0; k < K_; ++k) {
            const float* er = emb + k * D_;  // wave-uniform -> scalar loads

            // acc[j] holds SIMD lanes (2j, 2j+1); lane L accumulates d in
            // {L, L+16, L+32, L+48}: acc = fma(a0,b0, fma(a1,b1, fma(a2,b2, fma(a3,b3, 0))))
            v2f acc[8];
#pragma unroll
            for (int j = 0; j < 8; ++j) {
                int L = 2 * j;
                v2f ev, z;
                z[0] = 0.f; z[1] = 0.f;
                ev[0] = er[48 + L]; ev[1] = er[49 + L];
                acc[j] = __builtin_elementwise_fma(xr[(48 + L) >> 1], ev, z);
                ev[0] = er[32 + L]; ev[1] = er[33 + L];
                acc[j] = __builtin_elementwise_fma(xr[(32 + L) >> 1], ev, acc[j]);
                ev[0] = er[16 + L]; ev[1] = er[17 + L];
                acc[j] = __builtin_elementwise_fma(xr[(16 + L) >> 1], ev, acc[j]);
                ev[0] = er[0 + L];  ev[1] = er[1 + L];
                acc[j] = __builtin_elementwise_fma(xr[(0 + L) >> 1], ev, acc[j]);
            }

            // _mm512_reduce_add_ps tree: strides 8, 4, 2, 1 (pairwise)
            v2f s8_0 = acc[0] + acc[4];
            v2f s8_1 = acc[1] + acc[5];
            v2f s8_2 = acc[2] + acc[6];
            v2f s8_3 = acc[3] + acc[7];
            v2f s4_0 = s8_0 + s8_2;
            v2f s4_1 = s8_1 + s8_3;
            v2f s2   = s4_0 + s4_1;
            float xe = s2[0] + s2[1];

            // fl(x2 - 2*xe) via fma: 2*xe exact, single rounding -> identical
            float tt   = fmaf(-2.0f, xe, x2);
            float dist = tt + s_e2[k];

            if (dist < best) { best = dist; bi = k; }  // strict: first index wins
        }
    }

    // ---- epilogue: out0 = x + (q - x) elementwise fp32, out1 = q
    const float* q = emb + bi * D_;
    float* o0 = out + ((size_t)b * D_) * T_ + t;
    float* o1 = o0 + (size_t)B_ * D_ * T_;
    {
#pragma clang fp contract(off)
#pragma unroll
        for (int d = 0; d < D_; ++d) {
            float qd = q[d];
            float xd = XD(d);
            float diff = qd - xd;
            o0[(size_t)d * T_] = xd + diff;
            o1[(size_t)d * T_] = qd;
        }
    }
#undef XD
}

extern "C" void kernel_launch(void* const* d_in, const int* in_sizes, int n_in,
                              void* d_out, int out_size, void* d_ws, size_t ws_size,
                              hipStream_t stream) {
    const float* x   = (const float*)d_in[0];   // [B, D, T] fp32
    const float* emb = (const float*)d_in[1];   // [K, D] fp32
    float* out = (float*)d_out;                 // [2, B, D, T] fp32

    vq_kernel<<<dim3(T_ / 256, B_), dim3(256), 0, stream>>>(x, emb, out);
}

// Round 2
// 386.086 us; speedup vs baseline: 1.0037x; 1.0037x over previous
//
#include <hip/hip_runtime.h>
#include <cstddef>

// Problem constants (match reference): B=32, D=64, T=8192, K=512
#define B_ 32
#define D_ 64
#define T_ 8192
#define K_ 512

typedef float v2f __attribute__((ext_vector_type(2)));

// ---------------------------------------------------------------------------
// One thread per (b,t). Bit-replicates the numpy fp32 pipeline (verified
// absmax==0):
//   x2  = np.sum(xp*xp, -1)        -> pairwise 8-accumulator block (n=64)
//   e2  = np.sum(emb*emb, -1)      -> same pairwise scheme (precomputed in LDS)
//   xe  = np.einsum('btd,kd->btk') -> npyv AVX512 dot: 16 lanes, 4-deep fused
//                                     FMA chain + 8/4/2/1 pairwise reduce
//   dist = fma(-2, xe, x2) + e2    -> identical to (x2 - 2*xe) + e2 since
//                                     2*xe is exact and fma rounds once
//   argmin: strict <, first index wins (np.argmin tie-break)
//
// ROUND-4 CHANGE (instruction-stream control, zero arithmetic change):
//   R2/R3 rocprof: ~106 VALU instrs/k vs 44-instr ideal DAG; VGPR_Count=56
//   proves the 64-float x column is NOT arch-VGPR resident (AGPR copies /
//   SGPR->VGPR movs inject ~60 instrs/k).  Allocation hints failed twice.
//   Fix: emit the inner DAG as inline asm --
//     * 4-deep v_pk_fma_f32 chain per j-block, xr as "v" pairs (forces
//       arch-VGPR residency), emb pairs as "s" doubles (constant-bus SGPR
//       operand, no v_mov, loaded via merged s_load_dwordx16)
//     * 7 v_pk_add_f32 reduce tree (guaranteed packed adds)
//   Rounding per element identical to __builtin_elementwise_fma / '+'.
// ---------------------------------------------------------------------------
__global__ __launch_bounds__(256)
__attribute__((amdgpu_waves_per_eu(4, 4)))
void vq_kernel(const float* __restrict__ x,
               const float* __restrict__ emb,
               float* __restrict__ out) {
    __shared__ float s_e2[K_];

    // ---- e2 precompute into LDS, numpy pairwise-8 order, no FMA contraction
    {
#pragma clang fp contract(off)
        for (int k = threadIdx.x; k < K_; k += 256) {
            const float* er = emb + k * D_;
            float r[8];
#pragma unroll
            for (int j = 0; j < 8; ++j) r[j] = er[j] * er[j];
#pragma unroll
            for (int i = 8; i < 64; i += 8) {
#pragma unroll
                for (int j = 0; j < 8; ++j) {
                    float p = er[i + j] * er[i + j];
                    r[j] = r[j] + p;
                }
            }
            s_e2[k] = ((r[0] + r[1]) + (r[2] + r[3])) + ((r[4] + r[5]) + (r[6] + r[7]));
        }
    }
    __syncthreads();

    const int t = blockIdx.x * 256 + threadIdx.x;
    const int b = blockIdx.y;
    const float* xp = x + ((size_t)b * D_) * T_ + t;

    // ---- load x[b, :, t] into 32 packed v2f regs (coalesced across lanes)
    v2f xr[D_ / 2];
#pragma unroll
    for (int j = 0; j < D_ / 2; ++j) {
        v2f p;
        p[0] = xp[(size_t)(2 * j) * T_];
        p[1] = xp[(size_t)(2 * j + 1) * T_];
        xr[j] = p;
    }
    // Value barriers: make xr defs opaque (no remat / no sinking).
    asm volatile("" : "+v"(xr[0]), "+v"(xr[1]), "+v"(xr[2]), "+v"(xr[3]),
                      "+v"(xr[4]), "+v"(xr[5]), "+v"(xr[6]), "+v"(xr[7]));
    asm volatile("" : "+v"(xr[8]), "+v"(xr[9]), "+v"(xr[10]), "+v"(xr[11]),
                      "+v"(xr[12]), "+v"(xr[13]), "+v"(xr[14]), "+v"(xr[15]));
    asm volatile("" : "+v"(xr[16]), "+v"(xr[17]), "+v"(xr[18]), "+v"(xr[19]),
                      "+v"(xr[20]), "+v"(xr[21]), "+v"(xr[22]), "+v"(xr[23]));
    asm volatile("" : "+v"(xr[24]), "+v"(xr[25]), "+v"(xr[26]), "+v"(xr[27]),
                      "+v"(xr[28]), "+v"(xr[29]), "+v"(xr[30]), "+v"(xr[31]));
#define XD(d) (xr[(d) >> 1][(d) & 1])

    // ---- x2 via numpy pairwise-8 (products first, then sequential adds)
    float x2;
    {
#pragma clang fp contract(off)
        float r[8];
#pragma unroll
        for (int j = 0; j < 8; ++j) r[j] = XD(j) * XD(j);
#pragma unroll
        for (int i = 8; i < 64; i += 8) {
#pragma unroll
            for (int j = 0; j < 8; ++j) {
                float p = XD(i + j) * XD(i + j);
                r[j] = r[j] + p;
            }
        }
        x2 = ((r[0] + r[1]) + (r[2] + r[3])) + ((r[4] + r[5]) + (r[6] + r[7]));
    }

    // zero v-pair for the fma-chain seed (hoisted out of the loop)
    v2f vzero;
    vzero[0] = 0.f; vzero[1] = 0.f;
    asm volatile("" : "+v"(vzero));

    // ---- K-loop: replicate einsum npyv dot (AVX512: vstep=16, one x4 iter)
    float best = 3.4e38f;
    int bi = 0;
    {
#pragma clang fp contract(off)
#pragma unroll 1
        for (int k = 0; k < K_; ++k) {
            const float* er = emb + k * D_;             // wave-uniform
            const double* erd = (const double*)er;      // aligned s-pairs

            // acc[j] holds npyv SIMD lanes (2j, 2j+1); lane L accumulates
            // d in {L, L+16, L+32, L+48}, chain order 48,32,16,0:
            //   acc = fma(x0,e0, fma(x16,e16, fma(x32,e32, fma(x48,e48, 0))))
            v2f acc[8];
#pragma unroll
            for (int j = 0; j < 8; ++j) {
                double ep48 = erd[24 + j];
                double ep32 = erd[16 + j];
                double ep16 = erd[8 + j];
                double ep0  = erd[j];
                v2f a;
                asm("v_pk_fma_f32 %0, %1, %5, %9\n\t"
                    "v_pk_fma_f32 %0, %2, %6, %0\n\t"
                    "v_pk_fma_f32 %0, %3, %7, %0\n\t"
                    "v_pk_fma_f32 %0, %4, %8, %0"
                    : "=&v"(a)
                    : "v"(xr[24 + j]), "v"(xr[16 + j]), "v"(xr[8 + j]), "v"(xr[j]),
                      "s"(ep48), "s"(ep32), "s"(ep16), "s"(ep0),
                      "v"(vzero));
                acc[j] = a;
            }

            // _mm512_reduce_add_ps tree: strides 8, 4, 2 (packed), then 1
            v2f s2v, q0, q1, q2, q3;
            asm("v_pk_add_f32 %1, %5, %9\n\t"
                "v_pk_add_f32 %2, %6, %10\n\t"
                "v_pk_add_f32 %3, %7, %11\n\t"
                "v_pk_add_f32 %4, %8, %12\n\t"
                "v_pk_add_f32 %1, %1, %3\n\t"
                "v_pk_add_f32 %2, %2, %4\n\t"
                "v_pk_add_f32 %0, %1, %2"
                : "=&v"(s2v), "=&v"(q0), "=&v"(q1), "=&v"(q2), "=&v"(q3)
                : "v"(acc[0]), "v"(acc[1]), "v"(acc[2]), "v"(acc[3]),
                  "v"(acc[4]), "v"(acc[5]), "v"(acc[6]), "v"(acc[7]));
            float xe = s2v[0] + s2v[1];

            // fl(x2 - 2*xe) via fma: 2*xe exact, single rounding -> identical
            float tt   = fmaf(-2.0f, xe, x2);
            float dist = tt + s_e2[k];

            if (dist < best) { best = dist; bi = k; }  // strict: first index wins
        }
    }

    // ---- epilogue: out0 = x + (q - x) elementwise fp32, out1 = q
    const float* q = emb + bi * D_;
    float* o0 = out + ((size_t)b * D_) * T_ + t;
    float* o1 = o0 + (size_t)B_ * D_ * T_;
    {
#pragma clang fp contract(off)
#pragma unroll
        for (int d = 0; d < D_; ++d) {
            float qd = q[d];
            float xd = XD(d);
            float diff = qd - xd;
            o0[(size_t)d * T_] = xd + diff;
            o1[(size_t)d * T_] = qd;
        }
    }
#undef XD
}

extern "C" void kernel_launch(void* const* d_in, const int* in_sizes, int n_in,
                              void* d_out, int out_size, void* d_ws, size_t ws_size,
                              hipStream_t stream) {
    const float* x   = (const float*)d_in[0];   // [B, D, T] fp32
    const float* emb = (const float*)d_in[1];   // [K, D] fp32
    float* out = (float*)d_out;                 // [2, B, D, T] fp32

    vq_kernel<<<dim3(T_ / 256, B_), dim3(256), 0, stream>>>(x, emb, out);
}

// Round 5
// 379.351 us; speedup vs baseline: 1.0215x; 1.0178x over previous
//
#include <hip/hip_runtime.h>
#include <cstddef>

// Problem constants (match reference): B=32, D=64, T=8192, K=512
#define B_ 32
#define D_ 64
#define T_ 8192
#define K_ 512

typedef float v2f __attribute__((ext_vector_type(2)));

// ---------------------------------------------------------------------------
// ROUND-7: whole-K-loop in ONE inline-asm block with fixed physical registers.
// R6 crashed: XL offsets were d*0x20000 (4x the real d-stride T*4=0x8000) ->
// OOB reads for b>=28 -> GPU memory fault. Fixed table d*0x8000.
// Also: pk-fma seed uses VGPR zero pair v[96:97] (the exact operand form
// validated absmax==0 in R4), and d_ws has a size guard with the R0 C++
// kernel as fallback.
//
// Evidence driving the asm approach (R1-R3): VGPR_Count=56 (< 64 needed for
// the x column) and constant VALU-busy ~181us across every source-level
// variant -> RA keeps x out of arch VGPRs and interposes ~60 copies/k.
// Fix: no RA inside the loop at all.
//
// Fixed-register map (inside the mega-asm):
//   v32..v95  : x[b,:,t] column, element d in v(32+d)
//   v96,v97   : zero pair (pk-fma seed); v97 doubles as addr temp in prologue
//   v98..v113 : 8 packed v2 accumulators (npyv lanes 2j,2j+1)
//   v114      : xe     v115: temp/dist     v116: x2    v117: k index
//   s36..s99  : current emb row, element d in s(36+d) (scalar-path fetch)
// e2 lives in d_ws (written by e2_kernel with the exact numpy pairwise-8
// arithmetic); main kernel has NO LDS and no __syncthreads.
//
// Bit-exactness: instruction-for-instruction the same fp32 DAG as the
// verified absmax==0 kernel: x2 pairwise-8; fma chain order 48,32,16,0 with
// fma(x,e,0) seed; 8/4/2/1 pairwise reduce; dist = fma(-2,xe,x2) + e2;
// argmin strict <, first index wins.
// ---------------------------------------------------------------------------

// x-column load: one dword per d, address = xbase + d*T*4 + t*4
#define XL(vr, off)                                   \
    "v_add_u32 v97, " off ", %[t4]\n\t"               \
    "global_load_dword " vr ", v97, %[xbase]\n\t"

// x2 pairwise-8 pieces
#define SQ0(rv, xv) "v_mul_f32 " rv ", " xv ", " xv "\n\t"
#define SQA(rv, xv)                                   \
    "v_mul_f32 v115, " xv ", " xv "\n\t"              \
    "v_add_f32 " rv ", " rv ", v115\n\t"

// packed fma: acc = x*e + acc   (seed variant: + 0 via zero VGPR pair)
#define PKF0(acc, xv, sv) "v_pk_fma_f32 " acc ", " xv ", " sv ", v[96:97]\n\t"
#define PKF(acc, xv, sv)  "v_pk_fma_f32 " acc ", " xv ", " sv ", " acc "\n\t"

__global__ void e2_kernel(const float* __restrict__ emb, float* __restrict__ e2) {
#pragma clang fp contract(off)
    int k = blockIdx.x * 256 + threadIdx.x;
    if (k < K_) {
        const float* er = emb + k * D_;
        float r[8];
#pragma unroll
        for (int j = 0; j < 8; ++j) r[j] = er[j] * er[j];
#pragma unroll
        for (int i = 8; i < 64; i += 8) {
#pragma unroll
            for (int j = 0; j < 8; ++j) {
                float p = er[i + j] * er[i + j];
                r[j] = r[j] + p;
            }
        }
        e2[k] = ((r[0] + r[1]) + (r[2] + r[3])) + ((r[4] + r[5]) + (r[6] + r[7]));
    }
}

__global__ __launch_bounds__(256)
__attribute__((amdgpu_waves_per_eu(4, 4)))
void vq_kernel(const float* __restrict__ x,
               const float* __restrict__ emb,
               const float* __restrict__ e2g,
               float* __restrict__ out) {
    const int t = blockIdx.x * 256 + threadIdx.x;
    const int b = blockIdx.y;
    const float* xb = x + (size_t)b * D_ * T_;   // uniform -> SGPR pair
    int t4 = t * 4;                              // per-lane byte offset

    const float* ep0 = emb;        // d 0..15 chunk base
    const float* ep1 = emb + 16;   // d 16..31
    const float* ep2 = emb + 32;   // d 32..47
    const float* ep3 = emb + 48;   // d 48..63

    float best = 3.4e38f;
    int bi = 0;
    int krow = 0, koff = 0, kk = 0;
    float e2s = 0.f;

    asm volatile(
        // ======== x column -> v32..v95 (offset = d * 0x8000 = d*T*4) ========
        XL("v32", "0x0")      XL("v33", "0x8000")   XL("v34", "0x10000")  XL("v35", "0x18000")
        XL("v36", "0x20000")  XL("v37", "0x28000")  XL("v38", "0x30000")  XL("v39", "0x38000")
        XL("v40", "0x40000")  XL("v41", "0x48000")  XL("v42", "0x50000")  XL("v43", "0x58000")
        XL("v44", "0x60000")  XL("v45", "0x68000")  XL("v46", "0x70000")  XL("v47", "0x78000")
        XL("v48", "0x80000")  XL("v49", "0x88000")  XL("v50", "0x90000")  XL("v51", "0x98000")
        XL("v52", "0xa0000")  XL("v53", "0xa8000")  XL("v54", "0xb0000")  XL("v55", "0xb8000")
        XL("v56", "0xc0000")  XL("v57", "0xc8000")  XL("v58", "0xd0000")  XL("v59", "0xd8000")
        XL("v60", "0xe0000")  XL("v61", "0xe8000")  XL("v62", "0xf0000")  XL("v63", "0xf8000")
        XL("v64", "0x100000") XL("v65", "0x108000") XL("v66", "0x110000") XL("v67", "0x118000")
        XL("v68", "0x120000") XL("v69", "0x128000") XL("v70", "0x130000") XL("v71", "0x138000")
        XL("v72", "0x140000") XL("v73", "0x148000") XL("v74", "0x150000") XL("v75", "0x158000")
        XL("v76", "0x160000") XL("v77", "0x168000") XL("v78", "0x170000") XL("v79", "0x178000")
        XL("v80", "0x180000") XL("v81", "0x188000") XL("v82", "0x190000") XL("v83", "0x198000")
        XL("v84", "0x1a0000") XL("v85", "0x1a8000") XL("v86", "0x1b0000") XL("v87", "0x1b8000")
        XL("v88", "0x1c0000") XL("v89", "0x1c8000") XL("v90", "0x1d0000") XL("v91", "0x1d8000")
        XL("v92", "0x1e0000") XL("v93", "0x1e8000") XL("v94", "0x1f0000") XL("v95", "0x1f8000")
        "s_waitcnt vmcnt(0)\n\t"
        // ================= x2 (numpy pairwise-8) -> v116 =================
        SQ0("v98", "v32") SQ0("v99", "v33") SQ0("v100", "v34") SQ0("v101", "v35")
        SQ0("v102", "v36") SQ0("v103", "v37") SQ0("v104", "v38") SQ0("v105", "v39")
        SQA("v98", "v40") SQA("v99", "v41") SQA("v100", "v42") SQA("v101", "v43")
        SQA("v102", "v44") SQA("v103", "v45") SQA("v104", "v46") SQA("v105", "v47")
        SQA("v98", "v48") SQA("v99", "v49") SQA("v100", "v50") SQA("v101", "v51")
        SQA("v102", "v52") SQA("v103", "v53") SQA("v104", "v54") SQA("v105", "v55")
        SQA("v98", "v56") SQA("v99", "v57") SQA("v100", "v58") SQA("v101", "v59")
        SQA("v102", "v60") SQA("v103", "v61") SQA("v104", "v62") SQA("v105", "v63")
        SQA("v98", "v64") SQA("v99", "v65") SQA("v100", "v66") SQA("v101", "v67")
        SQA("v102", "v68") SQA("v103", "v69") SQA("v104", "v70") SQA("v105", "v71")
        SQA("v98", "v72") SQA("v99", "v73") SQA("v100", "v74") SQA("v101", "v75")
        SQA("v102", "v76") SQA("v103", "v77") SQA("v104", "v78") SQA("v105", "v79")
        SQA("v98", "v80") SQA("v99", "v81") SQA("v100", "v82") SQA("v101", "v83")
        SQA("v102", "v84") SQA("v103", "v85") SQA("v104", "v86") SQA("v105", "v87")
        SQA("v98", "v88") SQA("v99", "v89") SQA("v100", "v90") SQA("v101", "v91")
        SQA("v102", "v92") SQA("v103", "v93") SQA("v104", "v94") SQA("v105", "v95")
        "v_add_f32 v106, v98, v99\n\t"
        "v_add_f32 v107, v100, v101\n\t"
        "v_add_f32 v108, v102, v103\n\t"
        "v_add_f32 v109, v104, v105\n\t"
        "v_add_f32 v106, v106, v107\n\t"
        "v_add_f32 v108, v108, v109\n\t"
        "v_add_f32 v116, v106, v108\n\t"
        // zero pair for pk-fma seed; k-index mirror for cndmask
        "v_mov_b32 v96, 0\n\t"
        "v_mov_b32 v97, 0\n\t"
        "v_mov_b32 v117, 0\n\t"
        // ================= prefetch row k=0 =================
        "s_load_dwordx16 s[36:51], %[embp0], %[krow]\n\t"
        "s_load_dwordx16 s[52:67], %[embp1], %[krow]\n\t"
        "s_load_dwordx16 s[68:83], %[embp2], %[krow]\n\t"
        "s_load_dwordx16 s[84:99], %[embp3], %[krow]\n\t"
        // ================= K loop =================
        "1:\n\t"
        "s_load_dword %[e2s], %[e2p], %[koff]\n\t"
        "s_waitcnt lgkmcnt(0)\n\t"
        // fma chain step 1: d=48..63 (seed with zero pair)
        PKF0("v[98:99]",   "v[80:81]", "s[84:85]")
        PKF0("v[100:101]", "v[82:83]", "s[86:87]")
        PKF0("v[102:103]", "v[84:85]", "s[88:89]")
        PKF0("v[104:105]", "v[86:87]", "s[90:91]")
        PKF0("v[106:107]", "v[88:89]", "s[92:93]")
        PKF0("v[108:109]", "v[90:91]", "s[94:95]")
        PKF0("v[110:111]", "v[92:93]", "s[96:97]")
        PKF0("v[112:113]", "v[94:95]", "s[98:99]")
        // step 2: d=32..47
        PKF("v[98:99]",   "v[64:65]", "s[68:69]")
        PKF("v[100:101]", "v[66:67]", "s[70:71]")
        PKF("v[102:103]", "v[68:69]", "s[72:73]")
        PKF("v[104:105]", "v[70:71]", "s[74:75]")
        PKF("v[106:107]", "v[72:73]", "s[76:77]")
        PKF("v[108:109]", "v[74:75]", "s[78:79]")
        PKF("v[110:111]", "v[76:77]", "s[80:81]")
        PKF("v[112:113]", "v[78:79]", "s[82:83]")
        // step 3: d=16..31
        PKF("v[98:99]",   "v[48:49]", "s[52:53]")
        PKF("v[100:101]", "v[50:51]", "s[54:55]")
        PKF("v[102:103]", "v[52:53]", "s[56:57]")
        PKF("v[104:105]", "v[54:55]", "s[58:59]")
        PKF("v[106:107]", "v[56:57]", "s[60:61]")
        PKF("v[108:109]", "v[58:59]", "s[62:63]")
        PKF("v[110:111]", "v[60:61]", "s[64:65]")
        PKF("v[112:113]", "v[62:63]", "s[66:67]")
        // step 4: d=0..15
        PKF("v[98:99]",   "v[32:33]", "s[36:37]")
        PKF("v[100:101]", "v[34:35]", "s[38:39]")
        PKF("v[102:103]", "v[36:37]", "s[40:41]")
        PKF("v[104:105]", "v[38:39]", "s[42:43]")
        PKF("v[106:107]", "v[40:41]", "s[44:45]")
        PKF("v[108:109]", "v[42:43]", "s[46:47]")
        PKF("v[110:111]", "v[44:45]", "s[48:49]")
        PKF("v[112:113]", "v[46:47]", "s[50:51]")
        // prefetch next row (wrap k=512 -> row 0; harmless, drained at end)
        "s_add_u32 %[krow], %[krow], 0x100\n\t"
        "s_and_b32 %[krow], %[krow], 0x1ffff\n\t"
        "s_load_dwordx16 s[36:51], %[embp0], %[krow]\n\t"
        "s_load_dwordx16 s[52:67], %[embp1], %[krow]\n\t"
        "s_load_dwordx16 s[68:83], %[embp2], %[krow]\n\t"
        "s_load_dwordx16 s[84:99], %[embp3], %[krow]\n\t"
        // reduce tree: strides 8,4,2 packed, then halves
        "v_pk_add_f32 v[98:99], v[98:99], v[106:107]\n\t"
        "v_pk_add_f32 v[100:101], v[100:101], v[108:109]\n\t"
        "v_pk_add_f32 v[102:103], v[102:103], v[110:111]\n\t"
        "v_pk_add_f32 v[104:105], v[104:105], v[112:113]\n\t"
        "v_pk_add_f32 v[98:99], v[98:99], v[102:103]\n\t"
        "v_pk_add_f32 v[100:101], v[100:101], v[104:105]\n\t"
        "v_pk_add_f32 v[98:99], v[98:99], v[100:101]\n\t"
        "v_add_f32 v114, v98, v99\n\t"
        // dist = fma(-2, xe, x2) + e2[k]
        "v_fma_f32 v115, -2.0, v114, v116\n\t"
        "v_add_f32 v115, %[e2s], v115\n\t"
        // argmin: strict <, first index wins (all-VGPR cndmask + vcc)
        "v_cmp_nlt_f32 vcc, v115, %[best]\n\t"
        "v_min_f32 %[best], v115, %[best]\n\t"
        "v_cndmask_b32 %[bi], v117, %[bi], vcc\n\t"
        "v_add_u32 v117, 1, v117\n\t"
        "s_add_u32 %[kk], %[kk], 1\n\t"
        "s_add_u32 %[koff], %[koff], 4\n\t"
        "s_cmp_lg_u32 %[kk], 0x200\n\t"
        "s_cbranch_scc1 1b\n\t"
        "s_waitcnt lgkmcnt(0)\n\t"   // drain dangling prefetch before RA reuse
        : [e2s] "+s"(e2s), [krow] "+s"(krow), [koff] "+s"(koff), [kk] "+s"(kk),
          [best] "+v"(best), [bi] "+v"(bi)
        : [t4] "v"(t4), [xbase] "s"(xb),
          [embp0] "s"(ep0), [embp1] "s"(ep1), [embp2] "s"(ep2), [embp3] "s"(ep3),
          [e2p] "s"(e2g)
        : "memory", "vcc", "scc",
          "v32","v33","v34","v35","v36","v37","v38","v39",
          "v40","v41","v42","v43","v44","v45","v46","v47",
          "v48","v49","v50","v51","v52","v53","v54","v55",
          "v56","v57","v58","v59","v60","v61","v62","v63",
          "v64","v65","v66","v67","v68","v69","v70","v71",
          "v72","v73","v74","v75","v76","v77","v78","v79",
          "v80","v81","v82","v83","v84","v85","v86","v87",
          "v88","v89","v90","v91","v92","v93","v94","v95",
          "v96","v97","v98","v99","v100","v101","v102","v103",
          "v104","v105","v106","v107","v108","v109","v110","v111",
          "v112","v113","v114","v115","v116","v117",
          "s36","s37","s38","s39",
          "s40","s41","s42","s43","s44","s45","s46","s47",
          "s48","s49","s50","s51","s52","s53","s54","s55",
          "s56","s57","s58","s59","s60","s61","s62","s63",
          "s64","s65","s66","s67","s68","s69","s70","s71",
          "s72","s73","s74","s75","s76","s77","s78","s79",
          "s80","s81","s82","s83","s84","s85","s86","s87",
          "s88","s89","s90","s91","s92","s93","s94","s95",
          "s96","s97","s98","s99");

    // ---- epilogue: out0 = x + (q - x) elementwise fp32, out1 = q
    // (x re-loaded from global: L1/L2-hot; values bit-identical)
    const float* q  = emb + bi * D_;
    const float* xp = x + (size_t)b * D_ * T_ + t;
    float* o0 = out + (size_t)b * D_ * T_ + t;
    float* o1 = o0 + (size_t)B_ * D_ * T_;
    {
#pragma clang fp contract(off)
#pragma unroll
        for (int d = 0; d < D_; ++d) {
            float qd = q[d];
            float xd = xp[(size_t)d * T_];
            float diff = qd - xd;
            o0[(size_t)d * T_] = xd + diff;
            o1[(size_t)d * T_] = qd;
        }
    }
}

#undef XL
#undef SQ0
#undef SQA
#undef PKF0
#undef PKF

// ---------------------------------------------------------------------------
// Fallback: the R0 C++ kernel (verified 377us, absmax==0) — used only if the
// harness workspace is too small for the e2 table.
// ---------------------------------------------------------------------------
__global__ __launch_bounds__(256, 4) void vq_kernel_fb(const float* __restrict__ x,
                                                       const float* __restrict__ emb,
                                                       float* __restrict__ out) {
    __shared__ float s_e2[K_];
    {
#pragma clang fp contract(off)
        for (int k = threadIdx.x; k < K_; k += 256) {
            const float* er = emb + k * D_;
            float r[8];
#pragma unroll
            for (int j = 0; j < 8; ++j) r[j] = er[j] * er[j];
#pragma unroll
            for (int i = 8; i < 64; i += 8) {
#pragma unroll
                for (int j = 0; j < 8; ++j) {
                    float p = er[i + j] * er[i + j];
                    r[j] = r[j] + p;
                }
            }
            s_e2[k] = ((r[0] + r[1]) + (r[2] + r[3])) + ((r[4] + r[5]) + (r[6] + r[7]));
        }
    }
    __syncthreads();

    const int t = blockIdx.x * 256 + threadIdx.x;
    const int b = blockIdx.y;
    const float* xp = x + ((size_t)b * D_) * T_ + t;

    v2f xr[D_ / 2];
#pragma unroll
    for (int j = 0; j < D_ / 2; ++j) {
        v2f p;
        p[0] = xp[(size_t)(2 * j) * T_];
        p[1] = xp[(size_t)(2 * j + 1) * T_];
        xr[j] = p;
    }
#define XD(d) (xr[(d) >> 1][(d) & 1])

    float x2;
    {
#pragma clang fp contract(off)
        float r[8];
#pragma unroll
        for (int j = 0; j < 8; ++j) r[j] = XD(j) * XD(j);
#pragma unroll
        for (int i = 8; i < 64; i += 8) {
#pragma unroll
            for (int j = 0; j < 8; ++j) {
                float p = XD(i + j) * XD(i + j);
                r[j] = r[j] + p;
            }
        }
        x2 = ((r[0] + r[1]) + (r[2] + r[3])) + ((r[4] + r[5]) + (r[6] + r[7]));
    }

    float best = 3.4e38f;
    int bi = 0;
    {
#pragma clang fp contract(off)
        for (int k = 0; k < K_; ++k) {
            const float* er = emb + k * D_;
            v2f acc[8];
#pragma unroll
            for (int j = 0; j < 8; ++j) {
                int L = 2 * j;
                v2f ev, z;
                z[0] = 0.f; z[1] = 0.f;
                ev[0] = er[48 + L]; ev[1] = er[49 + L];
                acc[j] = __builtin_elementwise_fma(xr[(48 + L) >> 1], ev, z);
                ev[0] = er[32 + L]; ev[1] = er[33 + L];
                acc[j] = __builtin_elementwise_fma(xr[(32 + L) >> 1], ev, acc[j]);
                ev[0] = er[16 + L]; ev[1] = er[17 + L];
                acc[j] = __builtin_elementwise_fma(xr[(16 + L) >> 1], ev, acc[j]);
                ev[0] = er[0 + L];  ev[1] = er[1 + L];
                acc[j] = __builtin_elementwise_fma(xr[(0 + L) >> 1], ev, acc[j]);
            }
            v2f s8_0 = acc[0] + acc[4];
            v2f s8_1 = acc[1] + acc[5];
            v2f s8_2 = acc[2] + acc[6];
            v2f s8_3 = acc[3] + acc[7];
            v2f s4_0 = s8_0 + s8_2;
            v2f s4_1 = s8_1 + s8_3;
            v2f s2   = s4_0 + s4_1;
            float xe = s2[0] + s2[1];
            float tt   = fmaf(-2.0f, xe, x2);
            float dist = tt + s_e2[k];
            if (dist < best) { best = dist; bi = k; }
        }
    }

    const float* q = emb + bi * D_;
    float* o0 = out + ((size_t)b * D_) * T_ + t;
    float* o1 = o0 + (size_t)B_ * D_ * T_;
    {
#pragma clang fp contract(off)
#pragma unroll
        for (int d = 0; d < D_; ++d) {
            float qd = q[d];
            float xd = XD(d);
            float diff = qd - xd;
            o0[(size_t)d * T_] = xd + diff;
            o1[(size_t)d * T_] = qd;
        }
    }
#undef XD
}

extern "C" void kernel_launch(void* const* d_in, const int* in_sizes, int n_in,
                              void* d_out, int out_size, void* d_ws, size_t ws_size,
                              hipStream_t stream) {
    const float* x   = (const float*)d_in[0];   // [B, D, T] fp32
    const float* emb = (const float*)d_in[1];   // [K, D] fp32
    float* out = (float*)d_out;                 // [2, B, D, T] fp32

    if (d_ws != nullptr && ws_size >= K_ * sizeof(float)) {
        float* e2ws = (float*)d_ws;             // K floats
        e2_kernel<<<dim3(2), dim3(256), 0, stream>>>(emb, e2ws);
        vq_kernel<<<dim3(T_ / 256, B_), dim3(256), 0, stream>>>(x, emb, e2ws, out);
    } else {
        vq_kernel_fb<<<dim3(T_ / 256, B_), dim3(256), 0, stream>>>(x, emb, out);
    }
}